// Round 1
// 610.791 us; speedup vs baseline: 1.0058x; 1.0058x over previous
//
#include <hip/hip_runtime.h>

// Problem constants (fixed by the reference module).
#define ROWS 8192
#define COLS 8192

typedef float f32x4 __attribute__((ext_vector_type(4)));
typedef int   i32x4 __attribute__((ext_vector_type(4)));

// --------------------------------------------------------------------------
// Kernel 1: build the flat column-gather index from the slice table.
// One block, 1024 threads. n_slices = 600 <= 1024.
//   col_idx[off_i .. off_i+L_i) = [s_i, e_i)   with off = exclusive prefix sum
// d_ws is re-poisoned before every timed call, so this must run every call.
// --------------------------------------------------------------------------
__global__ void build_idx_kernel(const int* __restrict__ slices, int n_slices,
                                 int* __restrict__ col_idx) {
    __shared__ int sh[1024];
    const int t = threadIdx.x;
    int s = 0, L = 0;
    if (t < n_slices) {
        s = slices[2 * t];
        const int e = slices[2 * t + 1];
        L = e - s;
    }
    sh[t] = L;
    __syncthreads();
    // Hillis-Steele inclusive scan over 1024 entries.
    #pragma unroll
    for (int d = 1; d < 1024; d <<= 1) {
        int v = (t >= d) ? sh[t - d] : 0;
        __syncthreads();
        sh[t] += v;
        __syncthreads();
    }
    if (t < n_slices) {
        const int off = sh[t] - L;  // exclusive prefix
        for (int i = 0; i < L; ++i) col_idx[off + i] = s + i;
    }
}

// --------------------------------------------------------------------------
// Kernel 2: the gather. out[r, p] = in[r, col_idx[p]].
// Each thread handles 4 consecutive output columns (int4 idx load, float4
// non-temporal store) x 8 rows. Stores are pure streaming traffic -> `nt`
// keeps them out of L2 so the input row-panels (256 KB per y-group, shared
// by all x-blocks of that y) stay L2-resident.
// --------------------------------------------------------------------------
__global__ void gather_kernel(const float* __restrict__ in,
                              const int* __restrict__ col_idx,
                              float* __restrict__ out, int cols_out) {
    const int p4 = (blockIdx.x * blockDim.x + threadIdx.x) * 4;
    if (p4 >= cols_out) return;
    const size_t r0 = (size_t)blockIdx.y * 8;

    if (p4 + 3 < cols_out) {
        // cols_out = 12500 is divisible by 4, so this is the only live path;
        // the scalar branch below is a safety net for other shapes.
        const i32x4 c = *reinterpret_cast<const i32x4*>(col_idx + p4);
        const float* inp = in + r0 * COLS;
        float* outp = out + r0 * (size_t)cols_out + p4;
        #pragma unroll
        for (int k = 0; k < 8; ++k) {
            f32x4 v;
            v.x = inp[c.x];
            v.y = inp[c.y];
            v.z = inp[c.z];
            v.w = inp[c.w];
            __builtin_nontemporal_store(v, reinterpret_cast<f32x4*>(outp));
            inp += COLS;
            outp += cols_out;
        }
    } else {
        for (int p = p4; p < cols_out; ++p) {
            const int c = col_idx[p];
            const float* inp = in + r0 * COLS + c;
            float* outp = out + r0 * (size_t)cols_out + p;
            #pragma unroll
            for (int k = 0; k < 8; ++k) {
                outp[(size_t)k * cols_out] = inp[(size_t)k * COLS];
            }
        }
    }
}

extern "C" void kernel_launch(void* const* d_in, const int* in_sizes, int n_in,
                              void* d_out, int out_size, void* d_ws, size_t ws_size,
                              hipStream_t stream) {
    const float* in = (const float*)d_in[0];
    const int* slices = (const int*)d_in[1];   // harness passes integer inputs as int32
    float* out = (float*)d_out;

    const int n_slices = in_sizes[1] / 2;      // [n_slices, 2] flat
    const int cols_out = out_size / ROWS;      // 12500

    int* col_idx = (int*)d_ws;                 // 12500 ints = 50 KB scratch

    build_idx_kernel<<<1, 1024, 0, stream>>>(slices, n_slices, col_idx);

    // 256 threads x 4 cols = 1024 output cols per block; y covers 8 rows/block.
    dim3 block(256, 1, 1);
    dim3 grid((cols_out + 1023) / 1024, ROWS / 8, 1);
    gather_kernel<<<grid, block, 0, stream>>>(in, col_idx, out, cols_out);
}